// Round 11
// baseline (92.503 us; speedup 1.0000x reference)
//
#include <hip/hip_runtime.h>
#include <hip/hip_bf16.h>
#include <string.h>

#define N 4096
#define D 512
#define NB 64            // N/64 regions; triangle regions = NB*(NB+1)/2 = 2080
#define NBLK (NB*(NB+1)/2)
#define MARGIN 0.5f
#define FINF __builtin_huge_valf()
#define UINF 0x7F800000u

typedef __attribute__((ext_vector_type(4))) float f32x4;
typedef long fp8x8;      // 8 packed fp8-e4m3 (i64 MFMA operand)

__device__ inline float wave_sum(float v){
  #pragma unroll
  for (int off=32; off>0; off>>=1) v += __shfl_down(v, off, 64);
  return v;
}

// Pass 0: X (f32) -> fp8 e4m3 (2 MB panel), f32 row squared norms,
// init the atomic min/max arrays.
__global__ __launch_bounds__(128) void prep_kernel(const float* __restrict__ X,
    unsigned char* __restrict__ Xq, float* __restrict__ sq,
    unsigned int* __restrict__ hp2u, unsigned int* __restrict__ nm2u){
  const int row = blockIdx.x;
  const int t = threadIdx.x;
  const float4 v = *(const float4*)(X + (size_t)row*D + t*4);
  int p0 = __builtin_amdgcn_cvt_pk_fp8_f32(v.x, v.y, 0, false);
  int p1 = __builtin_amdgcn_cvt_pk_fp8_f32(v.z, v.w, 0, false);
  unsigned int packed = (p0 & 0xFFFFu) | ((unsigned int)(p1 & 0xFFFFu) << 16);
  *(unsigned int*)(Xq + (size_t)row*D + t*4) = packed;
  float ss = v.x*v.x + v.y*v.y + v.z*v.z + v.w*v.w;
  ss = wave_sum(ss);
  __shared__ float red[2];
  if ((t & 63) == 0) red[t >> 6] = ss;
  __syncthreads();
  if (t == 0){
    sq[row] = red[0] + red[1];
    hp2u[row] = 0u;                 // max-accumulator (d^2 domain, >= 0)
    nm2u[row] = UINF;               // +inf: min-accumulator
  }
}

// Fused triangle GEMM (fp8 MFMA, 64x64 tiles, FULL K=512 staged in one shot)
// + hardest-pos/neg reductions. Exactly ONE vmcnt drain per block: 16 DMA
// issues back-to-back -> one __syncthreads -> unbroken ds_read+MFMA run.
// LDS slot s of row r holds global 16B-chunk s ^ (r&31)  (write side stays
// lane-contiguous 1 KB per issue; read side <=2-way bank aliasing = free).
__global__ __launch_bounds__(256,2) void gemm_fused(const unsigned char* __restrict__ Xq,
    const float* __restrict__ sq, const int* __restrict__ lab,
    unsigned int* __restrict__ hp2u, unsigned int* __restrict__ nm2u){
  __shared__ __align__(16) unsigned char As[64*512];   // 32 KB: full-K A panel
  __shared__ __align__(16) unsigned char Bs[64*512];   // 32 KB: full-K B panel
  __shared__ float sqi[64];
  __shared__ float sqj[64];
  __shared__ int labi_s[64];
  __shared__ int labj_s[64];
  __shared__ unsigned int hpl[64], nml[64];   // region-row combine
  __shared__ unsigned int hpc[64], nmc[64];   // region-col combine

  // XCD-contiguous mapping: XCD x gets regions [x*260, (x+1)*260) of the triangle.
  const int rid = (blockIdx.x & 7) * (NBLK/8) + (blockIdx.x >> 3);
  int rem = rid, bi = 0;
  while (rem >= NB - bi){ rem -= NB - bi; bi++; }
  const int bj = bi + rem;
  const int row0 = bi * 64, col0 = bj * 64;

  const int tid = threadIdx.x;
  const int wave = tid >> 6, lane = tid & 63;
  const int wr = (wave >> 1) * 32, wc = (wave & 1) * 32;   // wave's 32x32 quadrant
  const int fr = lane & 15, q = lane >> 4;

  if (tid < 64) {
    sqi[tid] = sq[row0 + tid]; sqj[tid] = sq[col0 + tid];
    labi_s[tid] = lab[row0 + tid]; labj_s[tid] = lab[col0 + tid];
    hpl[tid] = 0u; nml[tid] = UINF; hpc[tid] = 0u; nmc[tid] = UINF;
  }

  // Staging: per issue a wave covers 2 rows x 32 chunks (1 KB). Lane l:
  // local row = l>>5, slot = l&31, fetches global chunk (l&31) ^ (row&31).
  const int rlane = lane >> 5;
  const int s32 = lane & 31;
  #pragma unroll
  for (int c = 0; c < 8; ++c){
    const int rloc = c*8 + wave*2 + rlane;          // row within 64-row tile
    const int gch = s32 ^ (rloc & 31);
    const unsigned char* ga = Xq + (size_t)(row0 + rloc)*D + gch*16;
    const unsigned char* gb = Xq + (size_t)(col0 + rloc)*D + gch*16;
    const int dbase = (c*8 + wave*2) * 512;         // wave-uniform LDS base
    __builtin_amdgcn_global_load_lds((const __attribute__((address_space(1))) void*)ga,
        (__attribute__((address_space(3))) void*)(As + dbase), 16, 0, 0);
    __builtin_amdgcn_global_load_lds((const __attribute__((address_space(1))) void*)gb,
        (__attribute__((address_space(3))) void*)(Bs + dbase), 16, 0, 0);
  }

  f32x4 acc[2][2];
  #pragma unroll
  for (int a=0;a<2;a++)
    #pragma unroll
    for (int b=0;b<2;b++)
      acc[a][b] = (f32x4){0.f,0.f,0.f,0.f};

  __syncthreads();   // THE one drain: all 16 DMAs + LDS init complete

  // Fragments: A[m=fr][k = kb*32 + q*8 + j]; chunk c = kb*2 + (q>>1),
  // swizzled slot = c ^ (row&31), 8 B at intra-offset (q&1)*8.
  const int hb = (q & 1) * 8;
  #pragma unroll
  for (int kb = 0; kb < 16; ++kb){
    const int cch = kb*2 + (q >> 1);
    fp8x8 af[2], bf[2];
    #pragma unroll
    for (int a=0;a<2;a++){
      const int ra = wr + a*16 + fr;
      af[a] = *(const fp8x8*)(As + ra*512 + ((cch ^ (ra & 31))*16) + hb);
    }
    #pragma unroll
    for (int b=0;b<2;b++){
      const int rb = wc + b*16 + fr;
      bf[b] = *(const fp8x8*)(Bs + rb*512 + ((cch ^ (rb & 31))*16) + hb);
    }
    #pragma unroll
    for (int a=0;a<2;a++)
      #pragma unroll
      for (int b=0;b<2;b++)
        acc[a][b] = __builtin_amdgcn_mfma_f32_16x16x32_fp8_fp8(af[a], bf[b], acc[a][b], 0, 0, 0);
  }

  // Epilogue. C/D layout: col=lane&15, row=(lane>>4)*4+v (shape-determined).
  const int colq = lane & 15, g4 = lane >> 4, rowq = g4 * 4;
  int   labi_r[8]; float sqi_r[8];
  #pragma unroll
  for (int a=0;a<2;a++)
    #pragma unroll
    for (int v=0;v<4;v++){
      const int iloc = wr + a*16 + rowq + v;
      labi_r[a*4+v] = labi_s[iloc];
      sqi_r[a*4+v]  = sqi[iloc];
    }

  float pmax_r[8], nmin_r[8];
  #pragma unroll
  for (int k=0;k<8;k++){ pmax_r[k] = 0.f; nmin_r[k] = FINF; }
  float cpos[2], cmin[2];

  #pragma unroll
  for (int b=0;b<2;b++){
    const int jloc = wc + b*16 + colq;
    const float sj = sqj[jloc];
    const int lj = labj_s[jloc];
    float cp = 0.f, cn = FINF;
    #pragma unroll
    for (int a=0;a<2;a++)
      #pragma unroll
      for (int v=0;v<4;v++){
        const int k = a*4+v;
        const float d2 = fmaf(acc[a][b][v], -2.0f, sqi_r[k] + sj);
        const bool same = (labi_r[k] == lj);         // covers diag (i==j)
        const float sp = same ? d2 : 0.0f;           // positive candidate
        const float sn = same ? FINF : d2;           // negative candidate
        pmax_r[k] = fmaxf(pmax_r[k], sp);
        nmin_r[k] = fminf(nmin_r[k], sn);
        cp = fmaxf(cp, sp);
        cn = fminf(cn, sn);
      }
    cpos[b] = cp; cmin[b] = cn;
  }

  // Row-direction: xor-reduce across the 16 lanes sharing a row -> LDS atomic.
  #pragma unroll
  for (int k=0;k<8;k++){
    float p = pmax_r[k], n = nmin_r[k];
    #pragma unroll
    for (int m=1;m<16;m<<=1){
      p = fmaxf(p, __shfl_xor(p, m, 64));
      n = fminf(n, __shfl_xor(n, m, 64));
    }
    if (colq == 0){
      const int il = wr + (k>>2)*16 + rowq + (k&3);
      atomicMax(&hpl[il], __float_as_uint(p));                 // p >= 0
      atomicMin(&nml[il], __float_as_uint(fmaxf(n, 0.f)));     // clamp: monotone
    }
  }
  // Column-direction (symmetry): xor-reduce across the 4 lane-groups -> LDS atomic.
  #pragma unroll
  for (int b=0;b<2;b++){
    float p = cpos[b], n = cmin[b];
    p = fmaxf(p, __shfl_xor(p, 16, 64)); p = fmaxf(p, __shfl_xor(p, 32, 64));
    n = fminf(n, __shfl_xor(n, 16, 64)); n = fminf(n, __shfl_xor(n, 32, 64));
    if (g4 == 0){
      const int jl = wc + b*16 + colq;
      atomicMax(&hpc[jl], __float_as_uint(p));
      atomicMin(&nmc[jl], __float_as_uint(fmaxf(n, 0.f)));
    }
  }

  __syncthreads();
  // Global flush: threads 0-63 do region rows, 64-127 region cols.
  if (tid < 64){
    atomicMax(hp2u + row0 + tid, hpl[tid]);
    atomicMin(nm2u + row0 + tid, nml[tid]);
  } else if (tid < 128){
    const int t2 = tid - 64;
    atomicMax(hp2u + col0 + t2, hpc[t2]);
    atomicMin(nm2u + col0 + t2, nmc[t2]);
  }
}

// Final: loss = mean(sqrt(hp2)) + mean(max(margin - sqrt(nm2), 0)).
// 16 blocks (parallel latency) + one atomicAdd per block; out is pre-zeroed.
__global__ __launch_bounds__(256) void final_reduce(const unsigned int* __restrict__ hp2u,
    const unsigned int* __restrict__ nm2u, float* __restrict__ out){
  const int i = blockIdx.x * 256 + threadIdx.x;
  const float hp2 = __uint_as_float(hp2u[i]);
  const float nm2 = __uint_as_float(nm2u[i]);
  float s = sqrtf(hp2 + 1e-12f) + fmaxf(MARGIN - sqrtf(nm2 + 1e-12f), 0.f);
  s = wave_sum(s);
  __shared__ float r[4];
  if ((threadIdx.x & 63) == 0) r[threadIdx.x >> 6] = s;
  __syncthreads();
  if (threadIdx.x == 0)
    atomicAdd(out, (r[0] + r[1] + r[2] + r[3]) * (1.0f / (float)N));
}

extern "C" void kernel_launch(void* const* d_in, const int* in_sizes, int n_in,
                              void* d_out, int out_size, void* d_ws, size_t ws_size,
                              hipStream_t stream) {
  (void)in_sizes; (void)n_in; (void)out_size; (void)ws_size;
  const float* X  = (const float*)d_in[0];
  const int* lab  = (const int*)d_in[1];
  float* out      = (float*)d_out;

  char* ws = (char*)d_ws;
  unsigned char* Xq     = (unsigned char*)ws;                  // 2 MB fp8
  float* sq             = (float*)(Xq + (size_t)N * D);        // 16 KB
  unsigned int* hp2u    = (unsigned int*)(sq + N);             // 16 KB
  unsigned int* nm2u    = hp2u + N;                            // 16 KB

  hipMemsetAsync(d_out, 0, sizeof(float), stream);
  prep_kernel<<<N, 128, 0, stream>>>(X, Xq, sq, hp2u, nm2u);
  gemm_fused<<<NBLK, 256, 0, stream>>>(Xq, sq, lab, hp2u, nm2u);
  final_reduce<<<16, 256, 0, stream>>>(hp2u, nm2u, out);
}

// Round 12
// 85.006 us; speedup vs baseline: 1.0882x; 1.0882x over previous
//
#include <hip/hip_runtime.h>
#include <hip/hip_bf16.h>
#include <string.h>

#define N 4096
#define D 512
#define NB 64             // 64-row strips; triangle tiles = NB*(NB+1)/2 = 2080
#define NTILE (NB*(NB+1)/2)
#define NBLOCKS 512       // persistent-ish: ~4 tiles per block, 2 blocks/CU
#define MARGIN 0.5f
#define FINF __builtin_huge_valf()
#define UINF 0x7F800000u

#define AS1 __attribute__((address_space(1)))
#define AS3 __attribute__((address_space(3)))

typedef __attribute__((ext_vector_type(4))) float f32x4;
typedef long fp8x8;       // 8 packed fp8-e4m3 (i64 MFMA operand)

__device__ inline float wave_sum(float v){
  #pragma unroll
  for (int off=32; off>0; off>>=1) v += __shfl_down(v, off, 64);
  return v;
}

// Pass 0: X (f32) -> fp8 e4m3 (2 MB panel), f32 row squared norms,
// init the atomic min/max arrays.
__global__ __launch_bounds__(128) void prep_kernel(const float* __restrict__ X,
    unsigned char* __restrict__ Xq, float* __restrict__ sq,
    unsigned int* __restrict__ hp2u, unsigned int* __restrict__ nm2u){
  const int row = blockIdx.x;
  const int t = threadIdx.x;
  const float4 v = *(const float4*)(X + (size_t)row*D + t*4);
  int p0 = __builtin_amdgcn_cvt_pk_fp8_f32(v.x, v.y, 0, false);
  int p1 = __builtin_amdgcn_cvt_pk_fp8_f32(v.z, v.w, 0, false);
  unsigned int packed = (p0 & 0xFFFFu) | ((unsigned int)(p1 & 0xFFFFu) << 16);
  *(unsigned int*)(Xq + (size_t)row*D + t*4) = packed;
  float ss = v.x*v.x + v.y*v.y + v.z*v.z + v.w*v.w;
  ss = wave_sum(ss);
  __shared__ float red[2];
  if ((t & 63) == 0) red[t >> 6] = ss;
  __syncthreads();
  if (t == 0){
    sq[row] = red[0] + red[1];
    hp2u[row] = 0u;                 // max-accumulator (d^2 domain, >= 0)
    nm2u[row] = UINF;               // +inf: min-accumulator
  }
}

// Persistent-tile fused triangle GEMM (fp8 MFMA, 64x64 tiles, full-K panels).
// Each block owns a CONTIGUOUS run of ~4 triangle tiles -> mostly one strip:
// A staged once per strip, row accumulators live in registers across the
// strip, only B re-stages per tile (2 barriers). Col metadata via per-lane
// L1-hit global loads (no LDS, no extra barriers).
__global__ __launch_bounds__(256,2) void gemm_fused(const unsigned char* __restrict__ Xq,
    const float* __restrict__ sq, const int* __restrict__ lab,
    unsigned int* __restrict__ hp2u, unsigned int* __restrict__ nm2u){
  __shared__ __align__(16) unsigned char As[64*512];   // 32 KB: full-K A panel
  __shared__ __align__(16) unsigned char Bs[64*512];   // 32 KB: full-K B panel

  const int tid = threadIdx.x;
  const int wave = tid >> 6, lane = tid & 63;
  const int wr = (wave >> 1) * 32, wc = (wave & 1) * 32;  // wave's 32x32 quadrant
  const int fr = lane & 15, q = lane >> 4;
  const int hb = (q & 1) * 8;
  const int colq = lane & 15, g4 = lane >> 4, rowq = g4 * 4;

  // Staging lane geometry: per issue a wave covers 2 rows x 32 chunks (1 KB).
  // LDS slot s of row r holds global 16B-chunk s ^ (r&31) (R9-R11 verified).
  const int rlane = lane >> 5;
  const int s32 = lane & 31;

  // XCD-banded contiguous tile ranges: blk' bijective on [0,512).
  const int blk = (blockIdx.x & 7) * 64 + (blockIdx.x >> 3);
  int t        = (blk * NTILE) >> 9;        // /NBLOCKS
  const int t1 = ((blk + 1) * NTILE) >> 9;
  int bi = 0, cur = 0;                       // cur = first tile id of strip bi
  while (t >= cur + (NB - bi)) { cur += NB - bi; ++bi; }
  int staged_bi = -1;

  float pmax_r[8], nmin_r[8];               // per-strip row accumulators
  int   labi_r[8]; float sqi_r[8];

  for (; t < t1; ++t){
    while (t >= cur + (NB - bi)) { cur += NB - bi; ++bi; }
    const int bj = bi + (t - cur);
    const int row0 = bi * 64, col0 = bj * 64;
    const bool newstrip = (bi != staged_bi);

    // Strip change: flush previous strip's row accumulators (registers only).
    if (newstrip && staged_bi >= 0){
      const int prow0 = staged_bi * 64;
      #pragma unroll
      for (int k=0;k<8;k++){
        float p = pmax_r[k], n = nmin_r[k];
        #pragma unroll
        for (int m=1;m<16;m<<=1){
          p = fmaxf(p, __shfl_xor(p, m, 64));
          n = fminf(n, __shfl_xor(n, m, 64));
        }
        if (colq == 0){
          const int ig = prow0 + wr + (k>>2)*16 + rowq + (k&3);
          atomicMax(hp2u + ig, __float_as_uint(p));
          atomicMin(nm2u + ig, __float_as_uint(fmaxf(n, 0.f)));
        }
      }
    }

    __syncthreads();              // all waves done reading As/Bs of prev tile
    // Stage B (and A on strip change): 8 DMA issues/wave each.
    #pragma unroll
    for (int c = 0; c < 8; ++c){
      const int rloc = c*8 + wave*2 + rlane;
      const int gch = s32 ^ (rloc & 31);
      const unsigned char* gb = Xq + (size_t)(col0 + rloc)*D + gch*16;
      __builtin_amdgcn_global_load_lds((const AS1 void*)gb,
          (AS3 void*)(Bs + (c*8 + wave*2)*512), 16, 0, 0);
    }
    if (newstrip){
      #pragma unroll
      for (int c = 0; c < 8; ++c){
        const int rloc = c*8 + wave*2 + rlane;
        const int gch = s32 ^ (rloc & 31);
        const unsigned char* ga = Xq + (size_t)(row0 + rloc)*D + gch*16;
        __builtin_amdgcn_global_load_lds((const AS1 void*)ga,
            (AS3 void*)(As + (c*8 + wave*2)*512), 16, 0, 0);
      }
      #pragma unroll
      for (int k=0;k<8;k++){
        pmax_r[k] = 0.f; nmin_r[k] = FINF;
        const int ig = row0 + wr + (k>>2)*16 + rowq + (k&3);
        labi_r[k] = lab[ig]; sqi_r[k] = sq[ig];
      }
      staged_bi = bi;
    }
    __syncthreads();              // compiler drains vmcnt -> panels valid

    f32x4 acc[2][2];
    #pragma unroll
    for (int a=0;a<2;a++)
      #pragma unroll
      for (int b=0;b<2;b++)
        acc[a][b] = (f32x4){0.f,0.f,0.f,0.f};

    // K-loop: A[m=fr][k=kb*32+q*8+j]; chunk c = kb*2+(q>>1), slot c^(row&31).
    #pragma unroll
    for (int kb = 0; kb < 16; ++kb){
      const int cch = kb*2 + (q >> 1);
      fp8x8 af[2], bf[2];
      #pragma unroll
      for (int a=0;a<2;a++){
        const int ra = wr + a*16 + fr;
        af[a] = *(const fp8x8*)(As + ra*512 + ((cch ^ (ra & 31))*16) + hb);
      }
      #pragma unroll
      for (int b=0;b<2;b++){
        const int rb = wc + b*16 + fr;
        bf[b] = *(const fp8x8*)(Bs + rb*512 + ((cch ^ (rb & 31))*16) + hb);
      }
      #pragma unroll
      for (int a=0;a<2;a++)
        #pragma unroll
        for (int b=0;b<2;b++)
          acc[a][b] = __builtin_amdgcn_mfma_f32_16x16x32_fp8_fp8(af[a], bf[b], acc[a][b], 0, 0, 0);
    }

    // Tile epilogue. C/D layout: col=lane&15, row=(lane>>4)*4+v.
    float sjv[2]; int ljv[2];
    #pragma unroll
    for (int b=0;b<2;b++){
      const int jg = col0 + wc + b*16 + colq;
      sjv[b] = sq[jg]; ljv[b] = lab[jg];       // L1-hit per-lane loads
    }
    float cpos[2], cmin[2];
    #pragma unroll
    for (int b=0;b<2;b++){
      float cp = 0.f, cn = FINF;
      #pragma unroll
      for (int a=0;a<2;a++)
        #pragma unroll
        for (int v=0;v<4;v++){
          const int k = a*4+v;
          const float d2 = fmaf(acc[a][b][v], -2.0f, sqi_r[k] + sjv[b]);
          const bool same = (labi_r[k] == ljv[b]);   // covers diag (i==j)
          const float sp = same ? d2 : 0.0f;
          const float sn = same ? FINF : d2;
          pmax_r[k] = fmaxf(pmax_r[k], sp);          // row accs persist over strip
          nmin_r[k] = fminf(nmin_r[k], sn);
          cp = fmaxf(cp, sp);
          cn = fminf(cn, sn);
        }
      cpos[b] = cp; cmin[b] = cn;
    }
    // Col-direction (symmetry): reduce across the 4 lane-groups, flush now.
    #pragma unroll
    for (int b=0;b<2;b++){
      float p = cpos[b], n = cmin[b];
      p = fmaxf(p, __shfl_xor(p, 16, 64)); p = fmaxf(p, __shfl_xor(p, 32, 64));
      n = fminf(n, __shfl_xor(n, 16, 64)); n = fminf(n, __shfl_xor(n, 32, 64));
      if (g4 == 0){
        const int jg = col0 + wc + b*16 + colq;
        atomicMax(hp2u + jg, __float_as_uint(p));
        atomicMin(nm2u + jg, __float_as_uint(fmaxf(n, 0.f)));
      }
    }
  }

  // Final strip's row flush.
  if (staged_bi >= 0){
    const int prow0 = staged_bi * 64;
    #pragma unroll
    for (int k=0;k<8;k++){
      float p = pmax_r[k], n = nmin_r[k];
      #pragma unroll
      for (int m=1;m<16;m<<=1){
        p = fmaxf(p, __shfl_xor(p, m, 64));
        n = fminf(n, __shfl_xor(n, m, 64));
      }
      if (colq == 0){
        const int ig = prow0 + wr + (k>>2)*16 + rowq + (k&3);
        atomicMax(hp2u + ig, __float_as_uint(p));
        atomicMin(nm2u + ig, __float_as_uint(fmaxf(n, 0.f)));
      }
    }
  }
}

// Final: loss = mean(sqrt(hp2)) + mean(max(margin - sqrt(nm2), 0)).
// 16 blocks + one atomicAdd each; out pre-zeroed by async memset.
__global__ __launch_bounds__(256) void final_reduce(const unsigned int* __restrict__ hp2u,
    const unsigned int* __restrict__ nm2u, float* __restrict__ out){
  const int i = blockIdx.x * 256 + threadIdx.x;
  const float hp2 = __uint_as_float(hp2u[i]);
  const float nm2 = __uint_as_float(nm2u[i]);
  float s = sqrtf(hp2 + 1e-12f) + fmaxf(MARGIN - sqrtf(nm2 + 1e-12f), 0.f);
  s = wave_sum(s);
  __shared__ float r[4];
  if ((threadIdx.x & 63) == 0) r[threadIdx.x >> 6] = s;
  __syncthreads();
  if (threadIdx.x == 0)
    atomicAdd(out, (r[0] + r[1] + r[2] + r[3]) * (1.0f / (float)N));
}

extern "C" void kernel_launch(void* const* d_in, const int* in_sizes, int n_in,
                              void* d_out, int out_size, void* d_ws, size_t ws_size,
                              hipStream_t stream) {
  (void)in_sizes; (void)n_in; (void)out_size; (void)ws_size;
  const float* X  = (const float*)d_in[0];
  const int* lab  = (const int*)d_in[1];
  float* out      = (float*)d_out;

  char* ws = (char*)d_ws;
  unsigned char* Xq     = (unsigned char*)ws;                  // 2 MB fp8
  float* sq             = (float*)(Xq + (size_t)N * D);        // 16 KB
  unsigned int* hp2u    = (unsigned int*)(sq + N);             // 16 KB
  unsigned int* nm2u    = hp2u + N;                            // 16 KB

  hipMemsetAsync(d_out, 0, sizeof(float), stream);
  prep_kernel<<<N, 128, 0, stream>>>(X, Xq, sq, hp2u, nm2u);
  gemm_fused<<<NBLOCKS, 256, 0, stream>>>(Xq, sq, lab, hp2u, nm2u);
  final_reduce<<<16, 256, 0, stream>>>(hp2u, nm2u, out);
}